// Round 12
// baseline (370.076 us; speedup 1.0000x reference)
//
#include <hip/hip_runtime.h>
#include <math.h>

#define CAPV 2560

typedef __bf16 bf16x8 __attribute__((ext_vector_type(8)));
typedef float f32x4 __attribute__((ext_vector_type(4)));

__device__ __forceinline__ float wave_sum64(float v) {
#pragma unroll
  for (int o = 32; o; o >>= 1) v += __shfl_xor(v, o, 64);
  return v;
}

__device__ __forceinline__ float silu_f(float t) {
  return t * __builtin_amdgcn_rcpf(1.f + __expf(-t));
}

// ---------------- routing + weight packing: 17 blocks ----------------
// MFMA B-fragment layout (16x16x32 bf16): col = lane&15, k = c*32+(lane>>4)*8+j
//   k -> tap = k>>3 (dy = tap>>2, dx = tap&3; dx==3 is a zero pad slot), ci = k&7
// block 0: gates for all 256 patches + stem pack (BN scale folded) + img_cnt zero
// blocks 1..16: expert (le) pack
__global__ __launch_bounds__(256) void routing_kernel(
    const float* __restrict__ gate_w, const float* __restrict__ gate_b,
    const float* __restrict__ stem_w, const float* __restrict__ stem_sc,
    const float* __restrict__ exp_w,
    int* __restrict__ route_e, float* __restrict__ route_gate,
    int* __restrict__ route_cpre, int* __restrict__ route_Ce,
    __bf16* __restrict__ stemPack, __bf16* __restrict__ expPack,
    int* __restrict__ img_cnt, float* __restrict__ d_scalars) {
  const int tid = threadIdx.x;
  if (blockIdx.x > 0) {
    int le = blockIdx.x - 1;
    for (int i = tid; i < 1536; i += 256) {
      int c = i >> 9, rem = i & 511, ln = rem >> 3, j = rem & 7;
      int k = c * 32 + ((ln >> 4) << 3) + j;
      int cl = ln & 15;
      int tap = k >> 3, ci = k & 7;
      int dy = tap >> 2, dx = tap & 3;
      float v = 0.f;
      if (cl < 8 && dx < 3)
        v = exp_w[((le * 8 + cl) * 8 + ci) * 9 + dy * 3 + dx];
      expPack[le * 1536 + i] = (__bf16)v;
    }
    return;
  }
  if (tid < 64) img_cnt[tid] = 0;  // reset per-image arrival counters each launch
  // stem pack: same fragment layout, ci limited to 0..2, scale folded in
  for (int i = tid; i < 1536; i += 256) {
    int c = i >> 9, rem = i & 511, ln = rem >> 3, j = rem & 7;
    int k = c * 32 + ((ln >> 4) << 3) + j;
    int cl = ln & 15;
    int tap = k >> 3, ci = k & 7;
    int dy = tap >> 2, dx = tap & 3;
    float v = 0.f;
    if (cl < 8 && dx < 3 && ci < 3)
      v = stem_w[(cl * 3 + ci) * 9 + dy * 3 + dx] * stem_sc[cl];
    stemPack[i] = (__bf16)v;
  }

  // ---- trig table: 128 rows x 4 freqs (same table serves y and x) ----
  __shared__ float tS[128][4], tC[128][4];
  __shared__ float sS8[16][4], sC8[16][4];
  if (tid < 128) {
    float yv = -1.f + (2.f / 127.f) * (float)tid;
#pragma unroll
    for (int k = 0; k < 4; ++k) {
      float fr = 3.14159265358979323846f * (float)(1 << k);
      tS[tid][k] = sinf(fr * yv);
      tC[tid][k] = cosf(fr * yv);
    }
  }
  __syncthreads();
  if (tid < 64) {
    int g8 = tid >> 2, k = tid & 3;
    float s = 0.f, c = 0.f;
#pragma unroll
    for (int r = 0; r < 8; ++r) {
      s += tS[g8 * 8 + r][k];
      c += tC[g8 * 8 + r][k];
    }
    sS8[g8][k] = s * 0.125f;
    sC8[g8][k] = c * 0.125f;
  }
  __syncthreads();

  const int p = tid;
  const int lane = p & 63, wv = p >> 6;
  const int hp = p >> 4, wp = p & 15;

  float pool[18];
  pool[0] = -1.f + (2.f / 127.f) * ((float)(hp * 8) + 3.5f);
  pool[1] = -1.f + (2.f / 127.f) * ((float)(wp * 8) + 3.5f);
#pragma unroll
  for (int k = 0; k < 4; ++k) {
    pool[2 + 4 * k] = sS8[hp][k];
    pool[3 + 4 * k] = sC8[hp][k];
    pool[4 + 4 * k] = sS8[wp][k];
    pool[5 + 4 * k] = sC8[wp][k];
  }

  __shared__ float sWP[4][8];
  __shared__ float sWZ[4];
  __shared__ int sWCnt[4][8];
  __shared__ float sMeanP[8], sFrac[8];
  __shared__ float sAcc[2];
  if (p == 0) { sAcc[0] = 0.f; sAcc[1] = 0.f; }

  for (int l = 0; l < 2; ++l) {
    float logit[8];
#pragma unroll
    for (int e = 0; e < 8; ++e) logit[e] = gate_b[l * 8 + e];
#pragma unroll
    for (int c = 0; c < 18; ++c) {
      float pl = pool[c];
#pragma unroll
      for (int e = 0; e < 8; ++e)
        logit[e] = fmaf(pl, gate_w[(l * 18 + c) * 8 + e], logit[e]);
    }
    float mxv = logit[0]; int em = 0;
#pragma unroll
    for (int e = 1; e < 8; ++e)
      if (logit[e] > mxv) { mxv = logit[e]; em = e; }
    float pr[8]; float se = 0.f;
#pragma unroll
    for (int e = 0; e < 8; ++e) { pr[e] = expf(logit[e] - mxv); se += pr[e]; }
    float inv = 1.f / se;
#pragma unroll
    for (int e = 0; e < 8; ++e) pr[e] *= inv;
    float lse = mxv + logf(se);
    float gate_val = inv;

    unsigned long long meq[8];
#pragma unroll
    for (int e = 0; e < 8; ++e) meq[e] = __ballot(em == e);
    unsigned long long mm = meq[0];
#pragma unroll
    for (int e = 1; e < 8; ++e) mm = (em == e) ? meq[e] : mm;
    unsigned long long below = (2ull << lane) - 1ull;
    int cpre_w = (int)__popcll(mm & below);
    if (lane < 8) {
      unsigned long long t = meq[0];
#pragma unroll
      for (int e = 1; e < 8; ++e) t = (lane == e) ? meq[e] : t;
      sWCnt[wv][lane] = (int)__popcll(t);
    }
    float z2 = wave_sum64(lse * lse);
    if (lane == 0) sWZ[wv] = z2;
#pragma unroll
    for (int e = 0; e < 8; ++e) {
      float s = wave_sum64(pr[e]);
      if (lane == 0) sWP[wv][e] = s;
    }
    __syncthreads();

    int cpre = cpre_w;
#pragma unroll
    for (int w2 = 0; w2 < 4; ++w2)
      if (w2 < wv) cpre += sWCnt[w2][em];

    route_e[l * 256 + p] = em;
    route_gate[l * 256 + p] = gate_val;
    route_cpre[l * 256 + p] = cpre;

    if (p < 8) {
      int ce = sWCnt[0][p] + sWCnt[1][p] + sWCnt[2][p] + sWCnt[3][p];
      route_Ce[l * 8 + p] = ce;
      int kept = 0;
      for (int bb = 0; bb < 64; ++bb) {
        int r = CAPV - bb * ce;
        r = r < 0 ? 0 : r;
        kept += (r < ce ? r : ce);
      }
      sFrac[p] = (float)kept * (1.f / 16384.f);
      sMeanP[p] = (sWP[0][p] + sWP[1][p] + sWP[2][p] + sWP[3][p]) * (1.f / 256.f);
    }
    __syncthreads();
    if (p == 0) {
      float s = 0.f;
#pragma unroll
      for (int e = 0; e < 8; ++e) s += sMeanP[e] * sFrac[e];
      sAcc[1] += 8.f * s;
      sAcc[0] += (sWZ[0] + sWZ[1] + sWZ[2] + sWZ[3]) * (1.f / 256.f);
    }
    __syncthreads();
  }
  if (p == 0) { d_scalars[0] = sAcc[0]; d_scalars[1] = sAcc[1]; }
}

// ------- token kernel: 4 tokens/block; all convs MFMA; fused per-image finish -------
// FULL halo zero retained: the stem MFMA reads all 8 channel slots of sH; ci 3..7
// must be 0.0 (not garbage) because 0-weight x NaN-garbage = NaN (r8-r10 bug).
__global__ __launch_bounds__(256) void token_kernel(
    const float* __restrict__ X,
    const __bf16* __restrict__ stemPack, const float* __restrict__ stem_bi,
    const __bf16* __restrict__ expPack, const float* __restrict__ exp_b,
    const float* __restrict__ gn_s, const float* __restrict__ gn_b,
    const int* __restrict__ route_e, const float* __restrict__ route_gate,
    const int* __restrict__ route_cpre, const int* __restrict__ route_Ce,
    float* __restrict__ blk_sums, int* __restrict__ img_cnt,
    const float* __restrict__ w1, const float* __restrict__ b1,
    const float* __restrict__ w2, const float* __restrict__ b2,
    float* __restrict__ out) {
  const int g = blockIdx.x;
  const int b = g >> 6, r6 = g & 63;
  const int hp = r6 >> 2, wq = r6 & 3;      // 4 horizontally adjacent patches
  const int tid = threadIdx.x;
  const int w = tid >> 6, lane = tid & 63;  // wave == token
  const int p = hp * 16 + wq * 4 + w;

  // MFMA lane decomposition (shared by stem + both expert layers)
  const int col = lane & 15;       // output channel (valid < 8)
  const int gq = lane >> 4;        // k-quadrant / D row-group-of-4
  const int ay = (lane & 15) >> 3; // A: px>>3 within rowgroup
  const int ax = lane & 7;         // A: px&7
  const int dy_ = (gq >> 1) + 1, dx_ = (gq & 1) * 4 + 1;  // D -> (y,x) mapping

  __shared__ __align__(16) __bf16 sH[10][36][8];     // bf16 halo, ch-last (ci 0..2)
  __shared__ __align__(16) __bf16 sT[4][10][12][8];  // bf16 token buf, ch-last
  __shared__ float sRed[4][12];
  __shared__ int sIsLast;
  __shared__ float sH1f[32];

  // ---- routing data + B-fragment prefetch (stem + both layers) ----
  const int e0 = __builtin_amdgcn_readfirstlane(route_e[p]);
  const int e1 = __builtin_amdgcn_readfirstlane(route_e[256 + p]);
  const float gp0 = route_gate[p], gp1 = route_gate[256 + p];
  const int cp0 = route_cpre[p], cp1 = route_cpre[256 + p];
  const int Ce0 = route_Ce[e0], Ce1 = route_Ce[8 + e1];
  // col<8 mask keeps zero-padded D columns 8..15 out of GN stats / sums
  const float gate0 = (col < 8 && b * Ce0 + cp0 <= CAPV) ? gp0 : 0.f;
  const float gate1 = (col < 8 && b * Ce1 + cp1 <= CAPV) ? gp1 : 0.f;
  const int le0 = e0, le1 = 8 + e1;
  const bf16x8* sp = (const bf16x8*)stemPack;
  const bf16x8* bp0 = (const bf16x8*)(expPack + le0 * 1536);
  const bf16x8* bp1 = (const bf16x8*)(expPack + le1 * 1536);
  bf16x8 SB0 = sp[lane], SB1 = sp[64 + lane], SB2 = sp[128 + lane];
  bf16x8 B00 = bp0[lane], B01 = bp0[64 + lane], B02 = bp0[128 + lane];
  bf16x8 B10 = bp1[lane], B11 = bp1[64 + lane], B12 = bp1[128 + lane];

  // ---- phase 0: zero FULL halo (all 8 ch slots) + own-token border ring ----
  {
    float4 z4 = {0.f, 0.f, 0.f, 0.f};
    float4* h4 = (float4*)&sH[0][0][0];  // 10*36*8*2B = 5760 B = 360 float4
#pragma unroll
    for (int i = 0; i < 2; ++i) {
      int idx = tid + i * 256;
      if (idx < 360) h4[idx] = z4;
    }
  }
  if (lane < 56) {  // sT ring: rows 0,9 (12 cols) + cols 0,9,10,11 (rows 1..8)
    int row, c2;
    if (lane < 12) { row = 0; c2 = lane; }
    else if (lane < 24) { row = 9; c2 = lane - 12; }
    else { int q = lane - 24; row = 1 + (q >> 2); int m = q & 3; c2 = (m == 0) ? 0 : 8 + m; }
    int4 z = {0, 0, 0, 0};
    *(int4*)&sT[w][row][c2][0] = z;
  }
  __syncthreads();

  // ---- halo fill: 3 x 10 x 34 region, fp32 coalesced read -> bf16 ch-last ----
  const int gy0 = hp * 8 - 1, gx0 = wq * 32 - 1;
#pragma unroll
  for (int k = 0; k < 4; ++k) {
    int i = tid + k * 256;
    if (i < 1020) {
      int ci = i / 340, rem = i - ci * 340;
      int r = rem / 34, c = rem - r * 34;
      int gy = gy0 + r, gx = gx0 + c;
      if (gy >= 0 && gy < 128 && gx >= 0 && gx < 128)
        sH[r][c][ci] = (__bf16)X[((b * 3 + ci) * 128 + gy) * 128 + gx];
    }
  }
  __syncthreads();

  // ---- stem conv via MFMA (3->8ch, K=96, BN scale folded in B, bias in C) ----
  {
    const float bias = stem_bi[col & 7];
    f32x4 d0 = {bias, bias, bias, bias};
    f32x4 d1 = d0, d2 = d0, d3 = d0;
#pragma unroll
    for (int c = 0; c < 3; ++c) {
      const __bf16* ab = &sH[ay + c][w * 8 + ax + gq][0];  // 16B-aligned
      bf16x8 A0 = *(const bf16x8*)(ab);          // rowgroup stride = 2 rows
      bf16x8 A1 = *(const bf16x8*)(ab + 576);    // 36*8 = 288 elems/row
      bf16x8 A2 = *(const bf16x8*)(ab + 1152);
      bf16x8 A3 = *(const bf16x8*)(ab + 1728);
      bf16x8 Bc = (c == 0) ? SB0 : (c == 1) ? SB1 : SB2;
      d0 = __builtin_amdgcn_mfma_f32_16x16x32_bf16(A0, Bc, d0, 0, 0, 0);
      d1 = __builtin_amdgcn_mfma_f32_16x16x32_bf16(A1, Bc, d1, 0, 0, 0);
      d2 = __builtin_amdgcn_mfma_f32_16x16x32_bf16(A2, Bc, d2, 0, 0, 0);
      d3 = __builtin_amdgcn_mfma_f32_16x16x32_bf16(A3, Bc, d3, 0, 0, 0);
    }
    if (col < 8) {
#pragma unroll
      for (int rg = 0; rg < 4; ++rg) {
        f32x4 dr = (rg == 0) ? d0 : (rg == 1) ? d1 : (rg == 2) ? d2 : d3;
#pragma unroll
        for (int r = 0; r < 4; ++r) {
          float t = silu_f(dr[r]);
          sT[w][rg * 2 + dy_][dx_ + r][col] = (__bf16)t;
        }
      }
    }
  }
  // sT[w] is wave-private; in-wave DS ordering suffices (no barrier).

  const __bf16* abase = &sT[w][ay][ax + gq][0];
  const float bias0 = exp_b[le0 * 8 + (col & 7)];
  const float bias1 = exp_b[le1 * 8 + (col & 7)];
  const float sgs0 = gn_s[col & 7], sgb0 = gn_b[col & 7];

  float v1s, v1q;
  {
    // ---------- expert layer 0 (bias preloaded in C) ----------
    f32x4 a0 = {bias0, bias0, bias0, bias0};
    f32x4 a1 = a0, a2 = a0, a3 = a0;
#pragma unroll
    for (int c = 0; c < 3; ++c) {
      bf16x8 A0 = *(const bf16x8*)(abase + (0 * 192 + c * 96));
      bf16x8 A1 = *(const bf16x8*)(abase + (1 * 192 + c * 96));
      bf16x8 A2 = *(const bf16x8*)(abase + (2 * 192 + c * 96));
      bf16x8 A3 = *(const bf16x8*)(abase + (3 * 192 + c * 96));
      bf16x8 Bc = (c == 0) ? B00 : (c == 1) ? B01 : B02;
      a0 = __builtin_amdgcn_mfma_f32_16x16x32_bf16(A0, Bc, a0, 0, 0, 0);
      a1 = __builtin_amdgcn_mfma_f32_16x16x32_bf16(A1, Bc, a1, 0, 0, 0);
      a2 = __builtin_amdgcn_mfma_f32_16x16x32_bf16(A2, Bc, a2, 0, 0, 0);
      a3 = __builtin_amdgcn_mfma_f32_16x16x32_bf16(A3, Bc, a3, 0, 0, 0);
    }
    float v[16];
    float s = 0.f, q = 0.f;
#pragma unroll
    for (int rg = 0; rg < 4; ++rg) {
      f32x4 ar = (rg == 0) ? a0 : (rg == 1) ? a1 : (rg == 2) ? a2 : a3;
#pragma unroll
      for (int r = 0; r < 4; ++r) {
        float t = silu_f(ar[r]) * gate0;
        v[rg * 4 + r] = t;
        s += t;
        q += t * t;
      }
    }
    s += __shfl_xor(s, 16, 64); q += __shfl_xor(q, 16, 64);
    s += __shfl_xor(s, 32, 64); q += __shfl_xor(q, 32, 64);
    s += __shfl_xor(s, 1, 64);  q += __shfl_xor(q, 1, 64);
    float mu = s * (1.f / 128.f);
    float var = q * (1.f / 128.f) - mu * mu;
    float inv = rsqrtf(var + 1e-5f);
    float sc2 = inv * sgs0;
    float bi2 = fmaf(-mu, sc2, sgb0);
    if (col < 8) {
#pragma unroll
      for (int rg = 0; rg < 4; ++rg)
#pragma unroll
        for (int r = 0; r < 4; ++r) {
          float n = fmaf(v[rg * 4 + r], sc2, bi2);
          sT[w][rg * 2 + dy_][dx_ + r][col] = (__bf16)n;
        }
    }
  }
  {
    // ---------- expert layer 1 (bias preloaded in C) ----------
    f32x4 a0 = {bias1, bias1, bias1, bias1};
    f32x4 a1 = a0, a2 = a0, a3 = a0;
#pragma unroll
    for (int c = 0; c < 3; ++c) {
      bf16x8 A0 = *(const bf16x8*)(abase + (0 * 192 + c * 96));
      bf16x8 A1 = *(const bf16x8*)(abase + (1 * 192 + c * 96));
      bf16x8 A2 = *(const bf16x8*)(abase + (2 * 192 + c * 96));
      bf16x8 A3 = *(const bf16x8*)(abase + (3 * 192 + c * 96));
      bf16x8 Bc = (c == 0) ? B10 : (c == 1) ? B11 : B12;
      a0 = __builtin_amdgcn_mfma_f32_16x16x32_bf16(A0, Bc, a0, 0, 0, 0);
      a1 = __builtin_amdgcn_mfma_f32_16x16x32_bf16(A1, Bc, a1, 0, 0, 0);
      a2 = __builtin_amdgcn_mfma_f32_16x16x32_bf16(A2, Bc, a2, 0, 0, 0);
      a3 = __builtin_amdgcn_mfma_f32_16x16x32_bf16(A3, Bc, a3, 0, 0, 0);
    }
    float s = 0.f, q = 0.f;
#pragma unroll
    for (int rg = 0; rg < 4; ++rg) {
      f32x4 ar = (rg == 0) ? a0 : (rg == 1) ? a1 : (rg == 2) ? a2 : a3;
#pragma unroll
      for (int r = 0; r < 4; ++r) {
        float t = silu_f(ar[r]) * gate1;
        s += t;
        q += t * t;
      }
    }
    s += __shfl_xor(s, 16, 64); q += __shfl_xor(q, 16, 64);
    s += __shfl_xor(s, 32, 64); q += __shfl_xor(q, 32, 64);
    v1s = s;
    v1q = q + __shfl_xor(q, 1, 64);
  }

  if (lane < 8) sRed[w][lane] = v1s;                       // col==lane, gq==0
  if (lane < 8 && !(lane & 1)) sRed[w][8 + (lane >> 1)] = v1q;
  __syncthreads();
  if (tid < 12) {
    float bs = sRed[0][tid] + sRed[1][tid] + sRed[2][tid] + sRed[3][tid];
    __hip_atomic_store(&blk_sums[(size_t)g * 12 + tid], bs,
                       __ATOMIC_RELAXED, __HIP_MEMORY_SCOPE_AGENT);
  }
  // ---- fused finish: write -> fence -> barrier -> acq-rel signal -> last reads ----
  __threadfence();
  __syncthreads();
  if (tid == 0) {
    int prev = __hip_atomic_fetch_add(&img_cnt[b], 1,
                                      __ATOMIC_ACQ_REL, __HIP_MEMORY_SCOPE_AGENT);
    sIsLast = (prev == 63);
  }
  __syncthreads();
  if (sIsLast && tid < 64) {
    float l0[12];
#pragma unroll
    for (int j = 0; j < 12; ++j)
      l0[j] = __hip_atomic_load(&blk_sums[(size_t)(b * 64 + lane) * 12 + j],
                                __ATOMIC_RELAXED, __HIP_MEMORY_SCOPE_AGENT);
#pragma unroll
    for (int j = 0; j < 12; ++j) l0[j] = wave_sum64(l0[j]);

    float pooled[8];
#pragma unroll
    for (int c = 0; c < 8; ++c) {
      int gg = c >> 1;
      float mean_c = l0[c] * (1.f / 16384.f);
      float mug = (l0[2 * gg] + l0[2 * gg + 1]) * (1.f / 32768.f);
      float var = l0[8 + gg] * (1.f / 32768.f) - mug * mug;
      pooled[c] = fmaf((mean_c - mug) * rsqrtf(var + 1e-5f), gn_s[8 + c], gn_b[8 + c]);
    }
    if (lane < 32) {
      float h = b1[lane];
#pragma unroll
      for (int c = 0; c < 8; ++c) h = fmaf(pooled[c], w1[c * 32 + lane], h);
      float t = 0.7978845608028654f * fmaf(0.044715f * h * h, h, h);
      sH1f[lane] = 0.5f * h * (1.f + tanhf(t));
    }
    // single wave: in-wave DS ordering makes sH1f visible without a barrier
    for (int o = lane; o < 100; o += 64) {
      float v = b2[o];
#pragma unroll
      for (int j = 0; j < 32; ++j) v = fmaf(sH1f[j], w2[j * 100 + o], v);
      out[b * 100 + o] = v;
    }
  }
}

extern "C" void kernel_launch(void* const* d_in, const int* in_sizes, int n_in,
                              void* d_out, int out_size, void* d_ws, size_t ws_size,
                              hipStream_t stream) {
  const float* X       = (const float*)d_in[0];
  const float* stem_w  = (const float*)d_in[1];
  const float* stem_sc = (const float*)d_in[2];
  const float* stem_bi = (const float*)d_in[3];
  const float* gate_w  = (const float*)d_in[4];
  const float* gate_b  = (const float*)d_in[5];
  const float* exp_w   = (const float*)d_in[6];
  const float* exp_b   = (const float*)d_in[7];
  const float* gn_s    = (const float*)d_in[8];
  const float* gn_b    = (const float*)d_in[9];
  const float* w1      = (const float*)d_in[10];
  const float* b1      = (const float*)d_in[11];
  const float* w2      = (const float*)d_in[12];
  const float* b2      = (const float*)d_in[13];
  float* out = (float*)d_out;

  char* ws = (char*)d_ws;
  int* route_e      = (int*)(ws + 0);          // 512 ints
  int* route_cpre   = (int*)(ws + 2048);       // 512 ints
  int* route_Ce     = (int*)(ws + 4096);       // 16 ints
  float* route_gate = (float*)(ws + 4160);     // 512 floats
  int* img_cnt      = (int*)(ws + 6208);       // 64 ints
  __bf16* stemPack  = (__bf16*)(ws + 8192);    // 1536 bf16 (3 KiB)
  __bf16* expPack   = (__bf16*)(ws + 16384);   // 16*1536 bf16 (48 KiB)
  float* blk_sums   = (float*)(ws + 65536);    // 4096*12 floats (192 KiB)

  routing_kernel<<<17, 256, 0, stream>>>(gate_w, gate_b, stem_w, stem_sc, exp_w,
                                         route_e, route_gate, route_cpre,
                                         route_Ce, stemPack, expPack, img_cnt,
                                         out + 6400);
  token_kernel<<<4096, 256, 0, stream>>>(X, stemPack, stem_bi, expPack, exp_b,
                                         gn_s, gn_b, route_e, route_gate,
                                         route_cpre, route_Ce, blk_sums, img_cnt,
                                         w1, b1, w2, b2, out);
}

// Round 13
// 52.141 us; speedup vs baseline: 7.0976x; 7.0976x over previous
//
#include <hip/hip_runtime.h>
#include <math.h>

#define CAPV 2560

typedef __bf16 bf16x8 __attribute__((ext_vector_type(8)));
typedef float f32x4 __attribute__((ext_vector_type(4)));

__device__ __forceinline__ float wave_sum64(float v) {
#pragma unroll
  for (int o = 32; o; o >>= 1) v += __shfl_xor(v, o, 64);
  return v;
}

__device__ __forceinline__ float silu_f(float t) {
  return t * __builtin_amdgcn_rcpf(1.f + __expf(-t));
}

// ---------------- routing + weight packing: 17 blocks ----------------
// MFMA B-fragment layout (16x16x32 bf16): col = lane&15, k = c*32+(lane>>4)*8+j
//   k -> tap = k>>3 (dy = tap>>2, dx = tap&3; dx==3 is a zero pad slot), ci = k&7
// block 0: gates for all 256 patches + stem pack (BN scale folded)
// blocks 1..16: expert (le) pack
__global__ __launch_bounds__(256) void routing_kernel(
    const float* __restrict__ gate_w, const float* __restrict__ gate_b,
    const float* __restrict__ stem_w, const float* __restrict__ stem_sc,
    const float* __restrict__ exp_w,
    int* __restrict__ route_e, float* __restrict__ route_gate,
    int* __restrict__ route_cpre, int* __restrict__ route_Ce,
    __bf16* __restrict__ stemPack, __bf16* __restrict__ expPack,
    float* __restrict__ d_scalars) {
  const int tid = threadIdx.x;
  if (blockIdx.x > 0) {
    int le = blockIdx.x - 1;
    for (int i = tid; i < 1536; i += 256) {
      int c = i >> 9, rem = i & 511, ln = rem >> 3, j = rem & 7;
      int k = c * 32 + ((ln >> 4) << 3) + j;
      int cl = ln & 15;
      int tap = k >> 3, ci = k & 7;
      int dy = tap >> 2, dx = tap & 3;
      float v = 0.f;
      if (cl < 8 && dx < 3)
        v = exp_w[((le * 8 + cl) * 8 + ci) * 9 + dy * 3 + dx];
      expPack[le * 1536 + i] = (__bf16)v;
    }
    return;
  }
  // stem pack: same fragment layout, ci limited to 0..2, scale folded in
  for (int i = tid; i < 1536; i += 256) {
    int c = i >> 9, rem = i & 511, ln = rem >> 3, j = rem & 7;
    int k = c * 32 + ((ln >> 4) << 3) + j;
    int cl = ln & 15;
    int tap = k >> 3, ci = k & 7;
    int dy = tap >> 2, dx = tap & 3;
    float v = 0.f;
    if (cl < 8 && dx < 3 && ci < 3)
      v = stem_w[(cl * 3 + ci) * 9 + dy * 3 + dx] * stem_sc[cl];
    stemPack[i] = (__bf16)v;
  }

  // ---- trig table: 128 rows x 4 freqs (same table serves y and x) ----
  __shared__ float tS[128][4], tC[128][4];
  __shared__ float sS8[16][4], sC8[16][4];
  if (tid < 128) {
    float yv = -1.f + (2.f / 127.f) * (float)tid;
#pragma unroll
    for (int k = 0; k < 4; ++k) {
      float fr = 3.14159265358979323846f * (float)(1 << k);
      tS[tid][k] = sinf(fr * yv);
      tC[tid][k] = cosf(fr * yv);
    }
  }
  __syncthreads();
  if (tid < 64) {
    int g8 = tid >> 2, k = tid & 3;
    float s = 0.f, c = 0.f;
#pragma unroll
    for (int r = 0; r < 8; ++r) {
      s += tS[g8 * 8 + r][k];
      c += tC[g8 * 8 + r][k];
    }
    sS8[g8][k] = s * 0.125f;
    sC8[g8][k] = c * 0.125f;
  }
  __syncthreads();

  const int p = tid;
  const int lane = p & 63, wv = p >> 6;
  const int hp = p >> 4, wp = p & 15;

  float pool[18];
  pool[0] = -1.f + (2.f / 127.f) * ((float)(hp * 8) + 3.5f);
  pool[1] = -1.f + (2.f / 127.f) * ((float)(wp * 8) + 3.5f);
#pragma unroll
  for (int k = 0; k < 4; ++k) {
    pool[2 + 4 * k] = sS8[hp][k];
    pool[3 + 4 * k] = sC8[hp][k];
    pool[4 + 4 * k] = sS8[wp][k];
    pool[5 + 4 * k] = sC8[wp][k];
  }

  __shared__ float sWP[4][8];
  __shared__ float sWZ[4];
  __shared__ int sWCnt[4][8];
  __shared__ float sMeanP[8], sFrac[8];
  __shared__ float sAcc[2];
  if (p == 0) { sAcc[0] = 0.f; sAcc[1] = 0.f; }

  for (int l = 0; l < 2; ++l) {
    float logit[8];
#pragma unroll
    for (int e = 0; e < 8; ++e) logit[e] = gate_b[l * 8 + e];
#pragma unroll
    for (int c = 0; c < 18; ++c) {
      float pl = pool[c];
#pragma unroll
      for (int e = 0; e < 8; ++e)
        logit[e] = fmaf(pl, gate_w[(l * 18 + c) * 8 + e], logit[e]);
    }
    float mxv = logit[0]; int em = 0;
#pragma unroll
    for (int e = 1; e < 8; ++e)
      if (logit[e] > mxv) { mxv = logit[e]; em = e; }
    float pr[8]; float se = 0.f;
#pragma unroll
    for (int e = 0; e < 8; ++e) { pr[e] = expf(logit[e] - mxv); se += pr[e]; }
    float inv = 1.f / se;
#pragma unroll
    for (int e = 0; e < 8; ++e) pr[e] *= inv;
    float lse = mxv + logf(se);
    float gate_val = inv;

    unsigned long long meq[8];
#pragma unroll
    for (int e = 0; e < 8; ++e) meq[e] = __ballot(em == e);
    unsigned long long mm = meq[0];
#pragma unroll
    for (int e = 1; e < 8; ++e) mm = (em == e) ? meq[e] : mm;
    unsigned long long below = (2ull << lane) - 1ull;
    int cpre_w = (int)__popcll(mm & below);
    if (lane < 8) {
      unsigned long long t = meq[0];
#pragma unroll
      for (int e = 1; e < 8; ++e) t = (lane == e) ? meq[e] : t;
      sWCnt[wv][lane] = (int)__popcll(t);
    }
    float z2 = wave_sum64(lse * lse);
    if (lane == 0) sWZ[wv] = z2;
#pragma unroll
    for (int e = 0; e < 8; ++e) {
      float s = wave_sum64(pr[e]);
      if (lane == 0) sWP[wv][e] = s;
    }
    __syncthreads();

    int cpre = cpre_w;
#pragma unroll
    for (int w2 = 0; w2 < 4; ++w2)
      if (w2 < wv) cpre += sWCnt[w2][em];

    route_e[l * 256 + p] = em;
    route_gate[l * 256 + p] = gate_val;
    route_cpre[l * 256 + p] = cpre;

    if (p < 8) {
      int ce = sWCnt[0][p] + sWCnt[1][p] + sWCnt[2][p] + sWCnt[3][p];
      route_Ce[l * 8 + p] = ce;
      int kept = 0;
      for (int bb = 0; bb < 64; ++bb) {
        int r = CAPV - bb * ce;
        r = r < 0 ? 0 : r;
        kept += (r < ce ? r : ce);
      }
      sFrac[p] = (float)kept * (1.f / 16384.f);
      sMeanP[p] = (sWP[0][p] + sWP[1][p] + sWP[2][p] + sWP[3][p]) * (1.f / 256.f);
    }
    __syncthreads();
    if (p == 0) {
      float s = 0.f;
#pragma unroll
      for (int e = 0; e < 8; ++e) s += sMeanP[e] * sFrac[e];
      sAcc[1] += 8.f * s;
      sAcc[0] += (sWZ[0] + sWZ[1] + sWZ[2] + sWZ[3]) * (1.f / 256.f);
    }
    __syncthreads();
  }
  if (p == 0) { d_scalars[0] = sAcc[0]; d_scalars[1] = sAcc[1]; }
}

// ------- token kernel: 4 tokens/block; all convs MFMA; bias preloaded in C -------
// FULL halo zero retained: stem MFMA reads all 8 channel slots of sH; ci 3..7
// must be 0.0 (not garbage) because 0-weight x NaN-garbage = NaN (r8-r10 bug).
__global__ __launch_bounds__(256) void token_kernel(
    const float* __restrict__ X,
    const __bf16* __restrict__ stemPack, const float* __restrict__ stem_bi,
    const __bf16* __restrict__ expPack, const float* __restrict__ exp_b,
    const float* __restrict__ gn_s, const float* __restrict__ gn_b,
    const int* __restrict__ route_e, const float* __restrict__ route_gate,
    const int* __restrict__ route_cpre, const int* __restrict__ route_Ce,
    float* __restrict__ blk_sums) {
  const int g = blockIdx.x;
  const int b = g >> 6, r6 = g & 63;
  const int hp = r6 >> 2, wq = r6 & 3;      // 4 horizontally adjacent patches
  const int tid = threadIdx.x;
  const int w = tid >> 6, lane = tid & 63;  // wave == token
  const int p = hp * 16 + wq * 4 + w;

  // MFMA lane decomposition (shared by stem + both expert layers)
  const int col = lane & 15;       // output channel (valid < 8)
  const int gq = lane >> 4;        // k-quadrant / D row-group-of-4
  const int ay = (lane & 15) >> 3; // A: px>>3 within rowgroup
  const int ax = lane & 7;         // A: px&7
  const int dy_ = (gq >> 1) + 1, dx_ = (gq & 1) * 4 + 1;  // D -> (y,x) mapping

  __shared__ __align__(16) __bf16 sH[10][36][8];     // bf16 halo, ch-last (ci 0..2)
  __shared__ __align__(16) __bf16 sT[4][10][12][8];  // bf16 token buf, ch-last
  __shared__ float sRed[4][12];

  // ---- routing data + B-fragment prefetch (stem + both layers) ----
  const int e0 = __builtin_amdgcn_readfirstlane(route_e[p]);
  const int e1 = __builtin_amdgcn_readfirstlane(route_e[256 + p]);
  const float gp0 = route_gate[p], gp1 = route_gate[256 + p];
  const int cp0 = route_cpre[p], cp1 = route_cpre[256 + p];
  const int Ce0 = route_Ce[e0], Ce1 = route_Ce[8 + e1];
  // col<8 mask keeps zero-padded D columns 8..15 out of GN stats / sums
  const float gate0 = (col < 8 && b * Ce0 + cp0 <= CAPV) ? gp0 : 0.f;
  const float gate1 = (col < 8 && b * Ce1 + cp1 <= CAPV) ? gp1 : 0.f;
  const int le0 = e0, le1 = 8 + e1;
  const bf16x8* sp = (const bf16x8*)stemPack;
  const bf16x8* bp0 = (const bf16x8*)(expPack + le0 * 1536);
  const bf16x8* bp1 = (const bf16x8*)(expPack + le1 * 1536);
  bf16x8 SB0 = sp[lane], SB1 = sp[64 + lane], SB2 = sp[128 + lane];
  bf16x8 B00 = bp0[lane], B01 = bp0[64 + lane], B02 = bp0[128 + lane];
  bf16x8 B10 = bp1[lane], B11 = bp1[64 + lane], B12 = bp1[128 + lane];

  // ---- phase 0: zero FULL halo (all 8 ch slots) + own-token border ring ----
  {
    float4 z4 = {0.f, 0.f, 0.f, 0.f};
    float4* h4 = (float4*)&sH[0][0][0];  // 10*36*8*2B = 5760 B = 360 float4
#pragma unroll
    for (int i = 0; i < 2; ++i) {
      int idx = tid + i * 256;
      if (idx < 360) h4[idx] = z4;
    }
  }
  if (lane < 56) {  // sT ring: rows 0,9 (12 cols) + cols 0,9,10,11 (rows 1..8)
    int row, c2;
    if (lane < 12) { row = 0; c2 = lane; }
    else if (lane < 24) { row = 9; c2 = lane - 12; }
    else { int q = lane - 24; row = 1 + (q >> 2); int m = q & 3; c2 = (m == 0) ? 0 : 8 + m; }
    int4 z = {0, 0, 0, 0};
    *(int4*)&sT[w][row][c2][0] = z;
  }
  __syncthreads();

  // ---- halo fill: 3 x 10 x 34 region, fp32 coalesced read -> bf16 ch-last ----
  const int gy0 = hp * 8 - 1, gx0 = wq * 32 - 1;
#pragma unroll
  for (int k = 0; k < 4; ++k) {
    int i = tid + k * 256;
    if (i < 1020) {
      int ci = i / 340, rem = i - ci * 340;
      int r = rem / 34, c = rem - r * 34;
      int gy = gy0 + r, gx = gx0 + c;
      if (gy >= 0 && gy < 128 && gx >= 0 && gx < 128)
        sH[r][c][ci] = (__bf16)X[((b * 3 + ci) * 128 + gy) * 128 + gx];
    }
  }
  __syncthreads();

  // ---- stem conv via MFMA (3->8ch, K=96, BN scale folded in B, bias in C) ----
  {
    const float bias = stem_bi[col & 7];
    f32x4 d0 = {bias, bias, bias, bias};
    f32x4 d1 = d0, d2 = d0, d3 = d0;
#pragma unroll
    for (int c = 0; c < 3; ++c) {
      const __bf16* ab = &sH[ay + c][w * 8 + ax + gq][0];  // 16B-aligned
      bf16x8 A0 = *(const bf16x8*)(ab);          // rowgroup stride = 2 rows
      bf16x8 A1 = *(const bf16x8*)(ab + 576);    // 36*8 = 288 elems/row
      bf16x8 A2 = *(const bf16x8*)(ab + 1152);
      bf16x8 A3 = *(const bf16x8*)(ab + 1728);
      bf16x8 Bc = (c == 0) ? SB0 : (c == 1) ? SB1 : SB2;
      d0 = __builtin_amdgcn_mfma_f32_16x16x32_bf16(A0, Bc, d0, 0, 0, 0);
      d1 = __builtin_amdgcn_mfma_f32_16x16x32_bf16(A1, Bc, d1, 0, 0, 0);
      d2 = __builtin_amdgcn_mfma_f32_16x16x32_bf16(A2, Bc, d2, 0, 0, 0);
      d3 = __builtin_amdgcn_mfma_f32_16x16x32_bf16(A3, Bc, d3, 0, 0, 0);
    }
    if (col < 8) {
#pragma unroll
      for (int rg = 0; rg < 4; ++rg) {
        f32x4 dr = (rg == 0) ? d0 : (rg == 1) ? d1 : (rg == 2) ? d2 : d3;
#pragma unroll
        for (int r = 0; r < 4; ++r) {
          float t = silu_f(dr[r]);
          sT[w][rg * 2 + dy_][dx_ + r][col] = (__bf16)t;
        }
      }
    }
  }
  // sT[w] is wave-private; in-wave DS ordering suffices (no barrier).

  const __bf16* abase = &sT[w][ay][ax + gq][0];
  const float bias0 = exp_b[le0 * 8 + (col & 7)];
  const float bias1 = exp_b[le1 * 8 + (col & 7)];
  const float sgs0 = gn_s[col & 7], sgb0 = gn_b[col & 7];

  float v1s, v1q;
  {
    // ---------- expert layer 0 (bias preloaded in C) ----------
    f32x4 a0 = {bias0, bias0, bias0, bias0};
    f32x4 a1 = a0, a2 = a0, a3 = a0;
#pragma unroll
    for (int c = 0; c < 3; ++c) {
      bf16x8 A0 = *(const bf16x8*)(abase + (0 * 192 + c * 96));
      bf16x8 A1 = *(const bf16x8*)(abase + (1 * 192 + c * 96));
      bf16x8 A2 = *(const bf16x8*)(abase + (2 * 192 + c * 96));
      bf16x8 A3 = *(const bf16x8*)(abase + (3 * 192 + c * 96));
      bf16x8 Bc = (c == 0) ? B00 : (c == 1) ? B01 : B02;
      a0 = __builtin_amdgcn_mfma_f32_16x16x32_bf16(A0, Bc, a0, 0, 0, 0);
      a1 = __builtin_amdgcn_mfma_f32_16x16x32_bf16(A1, Bc, a1, 0, 0, 0);
      a2 = __builtin_amdgcn_mfma_f32_16x16x32_bf16(A2, Bc, a2, 0, 0, 0);
      a3 = __builtin_amdgcn_mfma_f32_16x16x32_bf16(A3, Bc, a3, 0, 0, 0);
    }
    float v[16];
    float s = 0.f, q = 0.f;
#pragma unroll
    for (int rg = 0; rg < 4; ++rg) {
      f32x4 ar = (rg == 0) ? a0 : (rg == 1) ? a1 : (rg == 2) ? a2 : a3;
#pragma unroll
      for (int r = 0; r < 4; ++r) {
        float t = silu_f(ar[r]) * gate0;
        v[rg * 4 + r] = t;
        s += t;
        q += t * t;
      }
    }
    s += __shfl_xor(s, 16, 64); q += __shfl_xor(q, 16, 64);
    s += __shfl_xor(s, 32, 64); q += __shfl_xor(q, 32, 64);
    s += __shfl_xor(s, 1, 64);  q += __shfl_xor(q, 1, 64);
    float mu = s * (1.f / 128.f);
    float var = q * (1.f / 128.f) - mu * mu;
    float inv = rsqrtf(var + 1e-5f);
    float sc2 = inv * sgs0;
    float bi2 = fmaf(-mu, sc2, sgb0);
    if (col < 8) {
#pragma unroll
      for (int rg = 0; rg < 4; ++rg)
#pragma unroll
        for (int r = 0; r < 4; ++r) {
          float n = fmaf(v[rg * 4 + r], sc2, bi2);
          sT[w][rg * 2 + dy_][dx_ + r][col] = (__bf16)n;
        }
    }
  }
  {
    // ---------- expert layer 1 (bias preloaded in C) ----------
    f32x4 a0 = {bias1, bias1, bias1, bias1};
    f32x4 a1 = a0, a2 = a0, a3 = a0;
#pragma unroll
    for (int c = 0; c < 3; ++c) {
      bf16x8 A0 = *(const bf16x8*)(abase + (0 * 192 + c * 96));
      bf16x8 A1 = *(const bf16x8*)(abase + (1 * 192 + c * 96));
      bf16x8 A2 = *(const bf16x8*)(abase + (2 * 192 + c * 96));
      bf16x8 A3 = *(const bf16x8*)(abase + (3 * 192 + c * 96));
      bf16x8 Bc = (c == 0) ? B10 : (c == 1) ? B11 : B12;
      a0 = __builtin_amdgcn_mfma_f32_16x16x32_bf16(A0, Bc, a0, 0, 0, 0);
      a1 = __builtin_amdgcn_mfma_f32_16x16x32_bf16(A1, Bc, a1, 0, 0, 0);
      a2 = __builtin_amdgcn_mfma_f32_16x16x32_bf16(A2, Bc, a2, 0, 0, 0);
      a3 = __builtin_amdgcn_mfma_f32_16x16x32_bf16(A3, Bc, a3, 0, 0, 0);
    }
    float s = 0.f, q = 0.f;
#pragma unroll
    for (int rg = 0; rg < 4; ++rg) {
      f32x4 ar = (rg == 0) ? a0 : (rg == 1) ? a1 : (rg == 2) ? a2 : a3;
#pragma unroll
      for (int r = 0; r < 4; ++r) {
        float t = silu_f(ar[r]) * gate1;
        s += t;
        q += t * t;
      }
    }
    s += __shfl_xor(s, 16, 64); q += __shfl_xor(q, 16, 64);
    s += __shfl_xor(s, 32, 64); q += __shfl_xor(q, 32, 64);
    v1s = s;
    v1q = q + __shfl_xor(q, 1, 64);
  }

  if (lane < 8) sRed[w][lane] = v1s;                       // col==lane, gq==0
  if (lane < 8 && !(lane & 1)) sRed[w][8 + (lane >> 1)] = v1q;
  __syncthreads();
  if (tid < 12)
    blk_sums[(size_t)g * 12 + tid] =
        sRed[0][tid] + sRed[1][tid] + sRed[2][tid] + sRed[3][tid];
}

// ---------------- finish: per-image GN-folded pooling + MLP head ----------------
__global__ __launch_bounds__(64) void finish_kernel(
    const float* __restrict__ blk_sums,
    const float* __restrict__ gn_s, const float* __restrict__ gn_b,
    const float* __restrict__ w1, const float* __restrict__ b1,
    const float* __restrict__ w2, const float* __restrict__ b2,
    float* __restrict__ out) {
  const int b = blockIdx.x;
  const int lane = threadIdx.x;

  const float4* s4 = (const float4*)(blk_sums + (size_t)(b * 64 + lane) * 12);
  float4 a0 = s4[0], a1 = s4[1], a2 = s4[2];
  float l0[12] = {a0.x, a0.y, a0.z, a0.w, a1.x, a1.y, a1.z, a1.w,
                  a2.x, a2.y, a2.z, a2.w};
#pragma unroll
  for (int j = 0; j < 12; ++j) l0[j] = wave_sum64(l0[j]);

  float pooled[8];
#pragma unroll
  for (int c = 0; c < 8; ++c) {
    int gg = c >> 1;
    float mean_c = l0[c] * (1.f / 16384.f);
    float mug = (l0[2 * gg] + l0[2 * gg + 1]) * (1.f / 32768.f);
    float var = l0[8 + gg] * (1.f / 32768.f) - mug * mug;
    pooled[c] = fmaf((mean_c - mug) * rsqrtf(var + 1e-5f), gn_s[8 + c], gn_b[8 + c]);
  }

  __shared__ float sH1[32];
  if (lane < 32) {
    float h = b1[lane];
#pragma unroll
    for (int c = 0; c < 8; ++c) h = fmaf(pooled[c], w1[c * 32 + lane], h);
    float t = 0.7978845608028654f * fmaf(0.044715f * h * h, h, h);
    sH1[lane] = 0.5f * h * (1.f + tanhf(t));
  }
  __syncthreads();
  for (int o = lane; o < 100; o += 64) {
    float v = b2[o];
#pragma unroll
    for (int j = 0; j < 32; ++j) v = fmaf(sH1[j], w2[j * 100 + o], v);
    out[b * 100 + o] = v;
  }
}

extern "C" void kernel_launch(void* const* d_in, const int* in_sizes, int n_in,
                              void* d_out, int out_size, void* d_ws, size_t ws_size,
                              hipStream_t stream) {
  const float* X       = (const float*)d_in[0];
  const float* stem_w  = (const float*)d_in[1];
  const float* stem_sc = (const float*)d_in[2];
  const float* stem_bi = (const float*)d_in[3];
  const float* gate_w  = (const float*)d_in[4];
  const float* gate_b  = (const float*)d_in[5];
  const float* exp_w   = (const float*)d_in[6];
  const float* exp_b   = (const float*)d_in[7];
  const float* gn_s    = (const float*)d_in[8];
  const float* gn_b    = (const float*)d_in[9];
  const float* w1      = (const float*)d_in[10];
  const float* b1      = (const float*)d_in[11];
  const float* w2      = (const float*)d_in[12];
  const float* b2      = (const float*)d_in[13];
  float* out = (float*)d_out;

  char* ws = (char*)d_ws;
  int* route_e      = (int*)(ws + 0);          // 512 ints
  int* route_cpre   = (int*)(ws + 2048);       // 512 ints
  int* route_Ce     = (int*)(ws + 4096);       // 16 ints
  float* route_gate = (float*)(ws + 4160);     // 512 floats
  __bf16* stemPack  = (__bf16*)(ws + 8192);    // 1536 bf16 (3 KiB)
  __bf16* expPack   = (__bf16*)(ws + 16384);   // 16*1536 bf16 (48 KiB)
  float* blk_sums   = (float*)(ws + 65536);    // 4096*12 floats (192 KiB)

  routing_kernel<<<17, 256, 0, stream>>>(gate_w, gate_b, stem_w, stem_sc, exp_w,
                                         route_e, route_gate, route_cpre,
                                         route_Ce, stemPack, expPack, out + 6400);
  token_kernel<<<4096, 256, 0, stream>>>(X, stemPack, stem_bi, expPack, exp_b,
                                         gn_s, gn_b, route_e, route_gate,
                                         route_cpre, route_Ce, blk_sums);
  finish_kernel<<<64, 64, 0, stream>>>(blk_sums, gn_s, gn_b, w1, b1, w2, b2,
                                       out);
}

// Round 14
// 51.547 us; speedup vs baseline: 7.1794x; 1.0115x over previous
//
#include <hip/hip_runtime.h>
#include <math.h>

#define CAPV 2560

typedef __bf16 bf16x8 __attribute__((ext_vector_type(8)));
typedef float f32x4 __attribute__((ext_vector_type(4)));

__device__ __forceinline__ float wave_sum64(float v) {
#pragma unroll
  for (int o = 32; o; o >>= 1) v += __shfl_xor(v, o, 64);
  return v;
}

__device__ __forceinline__ float silu_f(float t) {
  return t * __builtin_amdgcn_rcpf(1.f + __expf(-t));
}

// ---------------- routing + weight packing: 17 blocks ----------------
// MFMA B-fragment layout (16x16x32 bf16): col = lane&15, k = c*32+(lane>>4)*8+j
//   k -> tap = k>>3 (dy = tap>>2, dx = tap&3; dx==3 is a zero pad slot), ci = k&7
// block 0: gates for all 256 patches + stem pack (BN scale folded)
// blocks 1..16: expert (le) pack
__global__ __launch_bounds__(256) void routing_kernel(
    const float* __restrict__ gate_w, const float* __restrict__ gate_b,
    const float* __restrict__ stem_w, const float* __restrict__ stem_sc,
    const float* __restrict__ exp_w,
    int* __restrict__ route_e, float* __restrict__ route_gate,
    int* __restrict__ route_cpre, int* __restrict__ route_Ce,
    __bf16* __restrict__ stemPack, __bf16* __restrict__ expPack,
    float* __restrict__ d_scalars) {
  const int tid = threadIdx.x;
  if (blockIdx.x > 0) {
    int le = blockIdx.x - 1;
    for (int i = tid; i < 1536; i += 256) {
      int c = i >> 9, rem = i & 511, ln = rem >> 3, j = rem & 7;
      int k = c * 32 + ((ln >> 4) << 3) + j;
      int cl = ln & 15;
      int tap = k >> 3, ci = k & 7;
      int dy = tap >> 2, dx = tap & 3;
      float v = 0.f;
      if (cl < 8 && dx < 3)
        v = exp_w[((le * 8 + cl) * 8 + ci) * 9 + dy * 3 + dx];
      expPack[le * 1536 + i] = (__bf16)v;
    }
    return;
  }
  // stem pack: same fragment layout, ci limited to 0..2, scale folded in
  for (int i = tid; i < 1536; i += 256) {
    int c = i >> 9, rem = i & 511, ln = rem >> 3, j = rem & 7;
    int k = c * 32 + ((ln >> 4) << 3) + j;
    int cl = ln & 15;
    int tap = k >> 3, ci = k & 7;
    int dy = tap >> 2, dx = tap & 3;
    float v = 0.f;
    if (cl < 8 && dx < 3 && ci < 3)
      v = stem_w[(cl * 3 + ci) * 9 + dy * 3 + dx] * stem_sc[cl];
    stemPack[i] = (__bf16)v;
  }

  // ---- trig table: 128 rows x 4 freqs (same table serves y and x) ----
  __shared__ float tS[128][4], tC[128][4];
  __shared__ float sS8[16][4], sC8[16][4];
  if (tid < 128) {
    float yv = -1.f + (2.f / 127.f) * (float)tid;
#pragma unroll
    for (int k = 0; k < 4; ++k) {
      float fr = 3.14159265358979323846f * (float)(1 << k);
      tS[tid][k] = sinf(fr * yv);
      tC[tid][k] = cosf(fr * yv);
    }
  }
  __syncthreads();
  if (tid < 64) {
    int g8 = tid >> 2, k = tid & 3;
    float s = 0.f, c = 0.f;
#pragma unroll
    for (int r = 0; r < 8; ++r) {
      s += tS[g8 * 8 + r][k];
      c += tC[g8 * 8 + r][k];
    }
    sS8[g8][k] = s * 0.125f;
    sC8[g8][k] = c * 0.125f;
  }
  __syncthreads();

  const int p = tid;
  const int lane = p & 63, wv = p >> 6;
  const int hp = p >> 4, wp = p & 15;

  float pool[18];
  pool[0] = -1.f + (2.f / 127.f) * ((float)(hp * 8) + 3.5f);
  pool[1] = -1.f + (2.f / 127.f) * ((float)(wp * 8) + 3.5f);
#pragma unroll
  for (int k = 0; k < 4; ++k) {
    pool[2 + 4 * k] = sS8[hp][k];
    pool[3 + 4 * k] = sC8[hp][k];
    pool[4 + 4 * k] = sS8[wp][k];
    pool[5 + 4 * k] = sC8[wp][k];
  }

  __shared__ float sWP[4][8];
  __shared__ float sWZ[4];
  __shared__ int sWCnt[4][8];
  __shared__ float sMeanP[8], sFrac[8];
  __shared__ float sAcc[2];
  if (p == 0) { sAcc[0] = 0.f; sAcc[1] = 0.f; }

  for (int l = 0; l < 2; ++l) {
    float logit[8];
#pragma unroll
    for (int e = 0; e < 8; ++e) logit[e] = gate_b[l * 8 + e];
#pragma unroll
    for (int c = 0; c < 18; ++c) {
      float pl = pool[c];
#pragma unroll
      for (int e = 0; e < 8; ++e)
        logit[e] = fmaf(pl, gate_w[(l * 18 + c) * 8 + e], logit[e]);
    }
    float mxv = logit[0]; int em = 0;
#pragma unroll
    for (int e = 1; e < 8; ++e)
      if (logit[e] > mxv) { mxv = logit[e]; em = e; }
    float pr[8]; float se = 0.f;
#pragma unroll
    for (int e = 0; e < 8; ++e) { pr[e] = expf(logit[e] - mxv); se += pr[e]; }
    float inv = 1.f / se;
#pragma unroll
    for (int e = 0; e < 8; ++e) pr[e] *= inv;
    float lse = mxv + logf(se);
    float gate_val = inv;

    unsigned long long meq[8];
#pragma unroll
    for (int e = 0; e < 8; ++e) meq[e] = __ballot(em == e);
    unsigned long long mm = meq[0];
#pragma unroll
    for (int e = 1; e < 8; ++e) mm = (em == e) ? meq[e] : mm;
    unsigned long long below = (2ull << lane) - 1ull;
    int cpre_w = (int)__popcll(mm & below);
    if (lane < 8) {
      unsigned long long t = meq[0];
#pragma unroll
      for (int e = 1; e < 8; ++e) t = (lane == e) ? meq[e] : t;
      sWCnt[wv][lane] = (int)__popcll(t);
    }
    float z2 = wave_sum64(lse * lse);
    if (lane == 0) sWZ[wv] = z2;
#pragma unroll
    for (int e = 0; e < 8; ++e) {
      float s = wave_sum64(pr[e]);
      if (lane == 0) sWP[wv][e] = s;
    }
    __syncthreads();

    int cpre = cpre_w;
#pragma unroll
    for (int w2 = 0; w2 < 4; ++w2)
      if (w2 < wv) cpre += sWCnt[w2][em];

    route_e[l * 256 + p] = em;
    route_gate[l * 256 + p] = gate_val;
    route_cpre[l * 256 + p] = cpre;

    if (p < 8) {
      int ce = sWCnt[0][p] + sWCnt[1][p] + sWCnt[2][p] + sWCnt[3][p];
      route_Ce[l * 8 + p] = ce;
      int kept = 0;
      for (int bb = 0; bb < 64; ++bb) {
        int r = CAPV - bb * ce;
        r = r < 0 ? 0 : r;
        kept += (r < ce ? r : ce);
      }
      sFrac[p] = (float)kept * (1.f / 16384.f);
      sMeanP[p] = (sWP[0][p] + sWP[1][p] + sWP[2][p] + sWP[3][p]) * (1.f / 256.f);
    }
    __syncthreads();
    if (p == 0) {
      float s = 0.f;
#pragma unroll
      for (int e = 0; e < 8; ++e) s += sMeanP[e] * sFrac[e];
      sAcc[1] += 8.f * s;
      sAcc[0] += (sWZ[0] + sWZ[1] + sWZ[2] + sWZ[3]) * (1.f / 256.f);
    }
    __syncthreads();
  }
  if (p == 0) { d_scalars[0] = sAcc[0]; d_scalars[1] = sAcc[1]; }
}

// --- token kernel: 8 tokens (2x4 patches) / 512-thread block; all convs MFMA ---
// FULL halo zero retained: stem MFMA reads all 8 channel slots of sH; ci 3..7
// must be 0.0 (not garbage) because 0-weight x NaN-garbage = NaN (r8-r10 bug).
__global__ __launch_bounds__(512) void token_kernel(
    const float* __restrict__ X,
    const __bf16* __restrict__ stemPack, const float* __restrict__ stem_bi,
    const __bf16* __restrict__ expPack, const float* __restrict__ exp_b,
    const float* __restrict__ gn_s, const float* __restrict__ gn_b,
    const int* __restrict__ route_e, const float* __restrict__ route_gate,
    const int* __restrict__ route_cpre, const int* __restrict__ route_Ce,
    float* __restrict__ blk_sums) {
  const int g = blockIdx.x;
  const int b = g >> 5, t5 = g & 31;
  const int tr = t5 >> 2, tc = t5 & 3;      // 2x4-patch tile (16x32 pixels)
  const int tid = threadIdx.x;
  const int w = tid >> 6, lane = tid & 63;  // wave == token; w = (row<<2)|col
  const int pr = tr * 2 + (w >> 2), pc = tc * 4 + (w & 3);
  const int p = pr * 16 + pc;

  // MFMA lane decomposition (shared by stem + both expert layers)
  const int col = lane & 15;       // output channel (valid < 8)
  const int gq = lane >> 4;        // k-quadrant / D row-group-of-4
  const int ay = (lane & 15) >> 3; // A: px>>3 within rowgroup
  const int ax = lane & 7;         // A: px&7
  const int dy_ = (gq >> 1) + 1, dx_ = (gq & 1) * 4 + 1;  // D -> (y,x) mapping

  __shared__ __align__(16) __bf16 sH[18][36][8];     // bf16 halo, ch-last (ci 0..2)
  __shared__ __align__(16) __bf16 sT[8][10][12][8];  // bf16 token buf, ch-last
  __shared__ float sRed[8][12];

  // ---- routing data + B-fragment prefetch (stem + both layers) ----
  const int e0 = __builtin_amdgcn_readfirstlane(route_e[p]);
  const int e1 = __builtin_amdgcn_readfirstlane(route_e[256 + p]);
  const float gp0 = route_gate[p], gp1 = route_gate[256 + p];
  const int cp0 = route_cpre[p], cp1 = route_cpre[256 + p];
  const int Ce0 = route_Ce[e0], Ce1 = route_Ce[8 + e1];
  // col<8 mask keeps zero-padded D columns 8..15 out of GN stats / sums
  const float gate0 = (col < 8 && b * Ce0 + cp0 <= CAPV) ? gp0 : 0.f;
  const float gate1 = (col < 8 && b * Ce1 + cp1 <= CAPV) ? gp1 : 0.f;
  const int le0 = e0, le1 = 8 + e1;
  const bf16x8* sp = (const bf16x8*)stemPack;
  const bf16x8* bp0 = (const bf16x8*)(expPack + le0 * 1536);
  const bf16x8* bp1 = (const bf16x8*)(expPack + le1 * 1536);
  bf16x8 SB0 = sp[lane], SB1 = sp[64 + lane], SB2 = sp[128 + lane];
  bf16x8 B00 = bp0[lane], B01 = bp0[64 + lane], B02 = bp0[128 + lane];
  bf16x8 B10 = bp1[lane], B11 = bp1[64 + lane], B12 = bp1[128 + lane];

  // ---- phase 0: zero FULL halo (all 8 ch slots) + own-token border ring ----
  {
    float4 z4 = {0.f, 0.f, 0.f, 0.f};
    float4* h4 = (float4*)&sH[0][0][0];  // 18*36*8*2B = 10368 B = 648 float4
#pragma unroll
    for (int i = 0; i < 2; ++i) {
      int idx = tid + i * 512;
      if (idx < 648) h4[idx] = z4;
    }
  }
  if (lane < 56) {  // sT ring: rows 0,9 (12 cols) + cols 0,9,10,11 (rows 1..8)
    int row, c2;
    if (lane < 12) { row = 0; c2 = lane; }
    else if (lane < 24) { row = 9; c2 = lane - 12; }
    else { int q = lane - 24; row = 1 + (q >> 2); int m = q & 3; c2 = (m == 0) ? 0 : 8 + m; }
    int4 z = {0, 0, 0, 0};
    *(int4*)&sT[w][row][c2][0] = z;
  }
  __syncthreads();

  // ---- halo fill: 3 x 18 x 34 region, fp32 coalesced read -> bf16 ch-last ----
  const int gy0 = tr * 16 - 1, gx0 = tc * 32 - 1;
#pragma unroll
  for (int k = 0; k < 4; ++k) {
    int i = tid + k * 512;
    if (i < 1836) {
      int ci = i / 612, rem = i - ci * 612;
      int r = rem / 34, c = rem - r * 34;
      int gy = gy0 + r, gx = gx0 + c;
      if (gy >= 0 && gy < 128 && gx >= 0 && gx < 128)
        sH[r][c][ci] = (__bf16)X[((b * 3 + ci) * 128 + gy) * 128 + gx];
    }
  }
  __syncthreads();

  // ---- stem conv via MFMA (3->8ch, K=96, BN scale folded in B, bias in C) ----
  const int hy0 = (w >> 2) * 8;          // wave's halo row base
  const int hx0 = (w & 3) * 8;           // wave's halo col base
  {
    const float bias = stem_bi[col & 7];
    f32x4 d0 = {bias, bias, bias, bias};
    f32x4 d1 = d0, d2 = d0, d3 = d0;
#pragma unroll
    for (int c = 0; c < 3; ++c) {
      const __bf16* ab = &sH[hy0 + ay + c][hx0 + ax + gq][0];  // 16B-aligned
      bf16x8 A0 = *(const bf16x8*)(ab);          // rowgroup stride = 2 rows
      bf16x8 A1 = *(const bf16x8*)(ab + 576);    // 36*8 = 288 elems/row
      bf16x8 A2 = *(const bf16x8*)(ab + 1152);
      bf16x8 A3 = *(const bf16x8*)(ab + 1728);
      bf16x8 Bc = (c == 0) ? SB0 : (c == 1) ? SB1 : SB2;
      d0 = __builtin_amdgcn_mfma_f32_16x16x32_bf16(A0, Bc, d0, 0, 0, 0);
      d1 = __builtin_amdgcn_mfma_f32_16x16x32_bf16(A1, Bc, d1, 0, 0, 0);
      d2 = __builtin_amdgcn_mfma_f32_16x16x32_bf16(A2, Bc, d2, 0, 0, 0);
      d3 = __builtin_amdgcn_mfma_f32_16x16x32_bf16(A3, Bc, d3, 0, 0, 0);
    }
    if (col < 8) {
#pragma unroll
      for (int rg = 0; rg < 4; ++rg) {
        f32x4 dr = (rg == 0) ? d0 : (rg == 1) ? d1 : (rg == 2) ? d2 : d3;
#pragma unroll
        for (int r = 0; r < 4; ++r) {
          float t = silu_f(dr[r]);
          sT[w][rg * 2 + dy_][dx_ + r][col] = (__bf16)t;
        }
      }
    }
  }
  // sT[w] is wave-private; in-wave DS ordering suffices (no barrier).

  const __bf16* abase = &sT[w][ay][ax + gq][0];
  const float bias0 = exp_b[le0 * 8 + (col & 7)];
  const float bias1 = exp_b[le1 * 8 + (col & 7)];
  const float sgs0 = gn_s[col & 7], sgb0 = gn_b[col & 7];

  float v1s, v1q;
  {
    // ---------- expert layer 0 (bias preloaded in C) ----------
    f32x4 a0 = {bias0, bias0, bias0, bias0};
    f32x4 a1 = a0, a2 = a0, a3 = a0;
#pragma unroll
    for (int c = 0; c < 3; ++c) {
      bf16x8 A0 = *(const bf16x8*)(abase + (0 * 192 + c * 96));
      bf16x8 A1 = *(const bf16x8*)(abase + (1 * 192 + c * 96));
      bf16x8 A2 = *(const bf16x8*)(abase + (2 * 192 + c * 96));
      bf16x8 A3 = *(const bf16x8*)(abase + (3 * 192 + c * 96));
      bf16x8 Bc = (c == 0) ? B00 : (c == 1) ? B01 : B02;
      a0 = __builtin_amdgcn_mfma_f32_16x16x32_bf16(A0, Bc, a0, 0, 0, 0);
      a1 = __builtin_amdgcn_mfma_f32_16x16x32_bf16(A1, Bc, a1, 0, 0, 0);
      a2 = __builtin_amdgcn_mfma_f32_16x16x32_bf16(A2, Bc, a2, 0, 0, 0);
      a3 = __builtin_amdgcn_mfma_f32_16x16x32_bf16(A3, Bc, a3, 0, 0, 0);
    }
    float v[16];
    float s = 0.f, q = 0.f;
#pragma unroll
    for (int rg = 0; rg < 4; ++rg) {
      f32x4 ar = (rg == 0) ? a0 : (rg == 1) ? a1 : (rg == 2) ? a2 : a3;
#pragma unroll
      for (int r = 0; r < 4; ++r) {
        float t = silu_f(ar[r]) * gate0;
        v[rg * 4 + r] = t;
        s += t;
        q += t * t;
      }
    }
    s += __shfl_xor(s, 16, 64); q += __shfl_xor(q, 16, 64);
    s += __shfl_xor(s, 32, 64); q += __shfl_xor(q, 32, 64);
    s += __shfl_xor(s, 1, 64);  q += __shfl_xor(q, 1, 64);
    float mu = s * (1.f / 128.f);
    float var = q * (1.f / 128.f) - mu * mu;
    float inv = rsqrtf(var + 1e-5f);
    float sc2 = inv * sgs0;
    float bi2 = fmaf(-mu, sc2, sgb0);
    if (col < 8) {
#pragma unroll
      for (int rg = 0; rg < 4; ++rg)
#pragma unroll
        for (int r = 0; r < 4; ++r) {
          float n = fmaf(v[rg * 4 + r], sc2, bi2);
          sT[w][rg * 2 + dy_][dx_ + r][col] = (__bf16)n;
        }
    }
  }
  {
    // ---------- expert layer 1 (bias preloaded in C) ----------
    f32x4 a0 = {bias1, bias1, bias1, bias1};
    f32x4 a1 = a0, a2 = a0, a3 = a0;
#pragma unroll
    for (int c = 0; c < 3; ++c) {
      bf16x8 A0 = *(const bf16x8*)(abase + (0 * 192 + c * 96));
      bf16x8 A1 = *(const bf16x8*)(abase + (1 * 192 + c * 96));
      bf16x8 A2 = *(const bf16x8*)(abase + (2 * 192 + c * 96));
      bf16x8 A3 = *(const bf16x8*)(abase + (3 * 192 + c * 96));
      bf16x8 Bc = (c == 0) ? B10 : (c == 1) ? B11 : B12;
      a0 = __builtin_amdgcn_mfma_f32_16x16x32_bf16(A0, Bc, a0, 0, 0, 0);
      a1 = __builtin_amdgcn_mfma_f32_16x16x32_bf16(A1, Bc, a1, 0, 0, 0);
      a2 = __builtin_amdgcn_mfma_f32_16x16x32_bf16(A2, Bc, a2, 0, 0, 0);
      a3 = __builtin_amdgcn_mfma_f32_16x16x32_bf16(A3, Bc, a3, 0, 0, 0);
    }
    float s = 0.f, q = 0.f;
#pragma unroll
    for (int rg = 0; rg < 4; ++rg) {
      f32x4 ar = (rg == 0) ? a0 : (rg == 1) ? a1 : (rg == 2) ? a2 : a3;
#pragma unroll
      for (int r = 0; r < 4; ++r) {
        float t = silu_f(ar[r]) * gate1;
        s += t;
        q += t * t;
      }
    }
    s += __shfl_xor(s, 16, 64); q += __shfl_xor(q, 16, 64);
    s += __shfl_xor(s, 32, 64); q += __shfl_xor(q, 32, 64);
    v1s = s;
    v1q = q + __shfl_xor(q, 1, 64);
  }

  if (lane < 8) sRed[w][lane] = v1s;                       // col==lane, gq==0
  if (lane < 8 && !(lane & 1)) sRed[w][8 + (lane >> 1)] = v1q;
  __syncthreads();
  if (tid < 12) {
    float bs = 0.f;
#pragma unroll
    for (int w2 = 0; w2 < 8; ++w2) bs += sRed[w2][tid];
    blk_sums[(size_t)g * 12 + tid] = bs;
  }
}

// ---------------- finish: per-image GN-folded pooling + MLP head ----------------
__global__ __launch_bounds__(64) void finish_kernel(
    const float* __restrict__ blk_sums,
    const float* __restrict__ gn_s, const float* __restrict__ gn_b,
    const float* __restrict__ w1, const float* __restrict__ b1,
    const float* __restrict__ w2, const float* __restrict__ b2,
    float* __restrict__ out) {
  const int b = blockIdx.x;
  const int lane = threadIdx.x;

  float l0[12] = {0.f, 0.f, 0.f, 0.f, 0.f, 0.f, 0.f, 0.f, 0.f, 0.f, 0.f, 0.f};
  if (lane < 32) {
    const float4* s4 = (const float4*)(blk_sums + (size_t)(b * 32 + lane) * 12);
    float4 a0 = s4[0], a1 = s4[1], a2 = s4[2];
    l0[0] = a0.x; l0[1] = a0.y; l0[2] = a0.z; l0[3] = a0.w;
    l0[4] = a1.x; l0[5] = a1.y; l0[6] = a1.z; l0[7] = a1.w;
    l0[8] = a2.x; l0[9] = a2.y; l0[10] = a2.z; l0[11] = a2.w;
  }
#pragma unroll
  for (int j = 0; j < 12; ++j) l0[j] = wave_sum64(l0[j]);

  float pooled[8];
#pragma unroll
  for (int c = 0; c < 8; ++c) {
    int gg = c >> 1;
    float mean_c = l0[c] * (1.f / 16384.f);
    float mug = (l0[2 * gg] + l0[2 * gg + 1]) * (1.f / 32768.f);
    float var = l0[8 + gg] * (1.f / 32768.f) - mug * mug;
    pooled[c] = fmaf((mean_c - mug) * rsqrtf(var + 1e-5f), gn_s[8 + c], gn_b[8 + c]);
  }

  __shared__ float sH1[32];
  if (lane < 32) {
    float h = b1[lane];
#pragma unroll
    for (int c = 0; c < 8; ++c) h = fmaf(pooled[c], w1[c * 32 + lane], h);
    float t = 0.7978845608028654f * fmaf(0.044715f * h * h, h, h);
    sH1[lane] = 0.5f * h * (1.f + tanhf(t));
  }
  __syncthreads();
  for (int o = lane; o < 100; o += 64) {
    float v = b2[o];
#pragma unroll
    for (int j = 0; j < 32; ++j) v = fmaf(sH1[j], w2[j * 100 + o], v);
    out[b * 100 + o] = v;
  }
}

extern "C" void kernel_launch(void* const* d_in, const int* in_sizes, int n_in,
                              void* d_out, int out_size, void* d_ws, size_t ws_size,
                              hipStream_t stream) {
  const float* X       = (const float*)d_in[0];
  const float* stem_w  = (const float*)d_in[1];
  const float* stem_sc = (const float*)d_in[2];
  const float* stem_bi = (const float*)d_in[3];
  const float* gate_w  = (const float*)d_in[4];
  const float* gate_b  = (const float*)d_in[5];
  const float* exp_w   = (const float*)d_in[6];
  const float* exp_b   = (const float*)d_in[7];
  const float* gn_s    = (const float*)d_in[8];
  const float* gn_b    = (const float*)d_in[9];
  const float* w1      = (const float*)d_in[10];
  const float* b1      = (const float*)d_in[11];
  const float* w2      = (const float*)d_in[12];
  const float* b2      = (const float*)d_in[13];
  float* out = (float*)d_out;

  char* ws = (char*)d_ws;
  int* route_e      = (int*)(ws + 0);          // 512 ints
  int* route_cpre   = (int*)(ws + 2048);       // 512 ints
  int* route_Ce     = (int*)(ws + 4096);       // 16 ints
  float* route_gate = (float*)(ws + 4160);     // 512 floats
  __bf16* stemPack  = (__bf16*)(ws + 8192);    // 1536 bf16 (3 KiB)
  __bf16* expPack   = (__bf16*)(ws + 16384);   // 16*1536 bf16 (48 KiB)
  float* blk_sums   = (float*)(ws + 65536);    // 2048*12 floats (96 KiB)

  routing_kernel<<<17, 256, 0, stream>>>(gate_w, gate_b, stem_w, stem_sc, exp_w,
                                         route_e, route_gate, route_cpre,
                                         route_Ce, stemPack, expPack, out + 6400);
  token_kernel<<<2048, 512, 0, stream>>>(X, stemPack, stem_bi, expPack, exp_b,
                                         gn_s, gn_b, route_e, route_gate,
                                         route_cpre, route_Ce, blk_sums);
  finish_kernel<<<64, 64, 0, stream>>>(blk_sums, gn_s, gn_b, w1, b1, w2, b2,
                                       out);
}